// Round 1
// baseline (98.214 us; speedup 1.0000x reference)
//
#include <hip/hip_runtime.h>

// FractalEmbedding: tokens -> Julia features (16 fp32) -> 16x2048 projection.
// Output 4*8192*2048 fp32 = 268 MB  => store-bandwidth-bound (~43 us roofline).

constexpr int TOKENS  = 4 * 8192;   // 32768
constexpr int EMBED   = 2048;
constexpr int NF      = 16;         // 2 * STEPS
constexpr int STEPS   = 8;
constexpr int THREADS = 512;        // each thread owns 4 consecutive d
constexpr int TB      = 64;         // tokens per block
constexpr int NBLOCKS = TOKENS / TB; // 512

__global__ __launch_bounds__(THREADS)
void fractal_embed_kernel(const int* __restrict__ tok,
                          const float* __restrict__ crt,
                          const float* __restrict__ cit,
                          const float* __restrict__ W,     // [2048][16]
                          const float* __restrict__ scale_p,
                          float* __restrict__ out)         // [TOKENS][2048]
{
    const int tid = threadIdx.x;
    const float s = scale_p[0];

    // ---- Load this thread's 4 rows of W (d = 4*tid .. 4*tid+3) into registers.
    // Rows are contiguous: floats [64*tid, 64*tid+64) -> 16 float4 loads.
    float w[4][NF];
    {
        const float4* W4 = reinterpret_cast<const float4*>(W + (size_t)tid * 4 * NF);
        #pragma unroll
        for (int r = 0; r < 4; ++r) {
            #pragma unroll
            for (int k = 0; k < 4; ++k) {
                float4 v = W4[r * 4 + k];
                w[r][k * 4 + 0] = v.x;
                w[r][k * 4 + 1] = v.y;
                w[r][k * 4 + 2] = v.z;
                w[r][k * 4 + 3] = v.w;
            }
        }
    }

    // ---- Stage Julia features for this block's 64 tokens into LDS (4 KB).
    __shared__ float feats[TB][NF];

    const int tok0 = blockIdx.x * TB;
    if (tid < TB) {
        const int t = tok[tok0 + tid];
        const float cr = crt[t];
        const float ci = cit[t];
        float zr = 0.0f, zi = 0.0f;
        #pragma unroll
        for (int st = 0; st < STEPS; ++st) {
            const float nzr = zr * zr - zi * zi + cr;
            const float nzi = 2.0f * zr * zi + ci;
            zr = nzr; zi = nzi;
            feats[tid][2 * st]     = zr;
            feats[tid][2 * st + 1] = zi;
        }
    }
    __syncthreads();

    // ---- For each token: broadcast-read feats, 64 FMAs, one float4 store.
    float4* __restrict__ out4 = reinterpret_cast<float4*>(out);
    for (int i = 0; i < TB; ++i) {
        float f[NF];
        {
            const float4* fp = reinterpret_cast<const float4*>(feats[i]);
            #pragma unroll
            for (int k = 0; k < 4; ++k) {
                float4 v = fp[k];
                f[k * 4 + 0] = v.x;
                f[k * 4 + 1] = v.y;
                f[k * 4 + 2] = v.z;
                f[k * 4 + 3] = v.w;
            }
        }
        float acc[4];
        #pragma unroll
        for (int r = 0; r < 4; ++r) {
            float a = 0.0f;
            #pragma unroll
            for (int k = 0; k < NF; ++k)
                a = fmaf(f[k], w[r][k], a);
            acc[r] = a * s;
        }
        float4 o;
        o.x = acc[0]; o.y = acc[1]; o.z = acc[2]; o.w = acc[3];
        out4[(size_t)(tok0 + i) * (EMBED / 4) + tid] = o;
    }
}

extern "C" void kernel_launch(void* const* d_in, const int* in_sizes, int n_in,
                              void* d_out, int out_size, void* d_ws, size_t ws_size,
                              hipStream_t stream) {
    const int*   tok   = (const int*)d_in[0];
    const float* crt   = (const float*)d_in[1];
    const float* cit   = (const float*)d_in[2];
    const float* W     = (const float*)d_in[3];
    const float* scale = (const float*)d_in[4];
    float*       out   = (float*)d_out;

    fractal_embed_kernel<<<NBLOCKS, THREADS, 0, stream>>>(tok, crt, cit, W, scale, out);
}

// Round 2
// 64.124 us; speedup vs baseline: 1.5316x; 1.5316x over previous
//
#include <hip/hip_runtime.h>

// FractalEmbedding: tokens -> Julia features (16 fp32) -> 16x2048 projection.
// Output 4*8192*2048 fp32 = 268 MB => store-bandwidth-bound (~38 us roofline
// at the 7 TB/s the harness memset itself achieves).
//
// R2 structure: kernel1 precomputes feats [32768][16] into d_ws (2 MB);
// kernel2 (256 thr/block, 2 dims/thread, w in 32 regs) reads feats through
// wave-uniform addresses (scalar-load candidates) and streams float2 stores.

constexpr int TOKENS = 4 * 8192;   // 32768
constexpr int EMBED  = 2048;
constexpr int NF     = 16;         // 2 * STEPS
constexpr int STEPS  = 8;

// ---------------- kernel 1: Julia features ----------------
__global__ __launch_bounds__(256)
void feats_kernel(const int* __restrict__ tok,
                  const float* __restrict__ crt,
                  const float* __restrict__ cit,
                  float* __restrict__ feats)   // [TOKENS][NF]
{
    const int t = blockIdx.x * 256 + threadIdx.x;
    const int id = tok[t];
    const float cr = crt[id];
    const float ci = cit[id];
    float f[NF];
    float zr = 0.0f, zi = 0.0f;
    #pragma unroll
    for (int st = 0; st < STEPS; ++st) {
        const float nzr = zr * zr - zi * zi + cr;
        const float nzi = 2.0f * zr * zi + ci;
        zr = nzr; zi = nzi;
        f[2 * st]     = zr;
        f[2 * st + 1] = zi;
    }
    float4* fo = reinterpret_cast<float4*>(feats + (size_t)t * NF);
    #pragma unroll
    for (int j = 0; j < 4; ++j)
        fo[j] = make_float4(f[4 * j], f[4 * j + 1], f[4 * j + 2], f[4 * j + 3]);
}

// ---------------- kernel 2: projection ----------------
// grid: 4 d-chunks (512 dims each) x 512 token-groups (64 tokens each) = 2048 blocks
constexpr int TB = 64;  // tokens per block

__global__ __launch_bounds__(256)
void proj_kernel(const float* __restrict__ feats,  // [TOKENS][NF]
                 const float* __restrict__ W,      // [EMBED][NF]
                 const float* __restrict__ scale_p,
                 float* __restrict__ out)          // [TOKENS][EMBED]
{
    const int tid  = threadIdx.x;
    const int dblk = blockIdx.x & 3;        // which 512-dim chunk
    const int tblk = blockIdx.x >> 2;       // which 64-token group
    const int d0   = dblk * 512 + tid * 2;  // this thread's 2 dims
    const float s  = scale_p[0];

    // 2 rows of W (32 floats, contiguous) -> registers, scale folded in.
    float w[2][NF];
    {
        const float4* W4 = reinterpret_cast<const float4*>(W + (size_t)d0 * NF);
        #pragma unroll
        for (int r = 0; r < 2; ++r) {
            #pragma unroll
            for (int k = 0; k < 4; ++k) {
                float4 v = W4[r * 4 + k];
                w[r][k * 4 + 0] = v.x * s;
                w[r][k * 4 + 1] = v.y * s;
                w[r][k * 4 + 2] = v.z * s;
                w[r][k * 4 + 3] = v.w * s;
            }
        }
    }

    const float* fbase = feats + (size_t)tblk * TB * NF;
    float2* __restrict__ out2 = reinterpret_cast<float2*>(out);
    const int obase = dblk * 256 + tid;     // in float2 units within a row

    #pragma unroll 2
    for (int i = 0; i < TB; ++i) {
        // Wave-uniform address: scalar-load candidate.
        float f[NF];
        {
            const float4* fp = reinterpret_cast<const float4*>(fbase + i * NF);
            #pragma unroll
            for (int k = 0; k < 4; ++k) {
                float4 v = fp[k];
                f[k * 4 + 0] = v.x;
                f[k * 4 + 1] = v.y;
                f[k * 4 + 2] = v.z;
                f[k * 4 + 3] = v.w;
            }
        }
        float a0 = 0.0f, a1 = 0.0f;
        #pragma unroll
        for (int k = 0; k < NF; ++k) {
            a0 = fmaf(f[k], w[0][k], a0);
            a1 = fmaf(f[k], w[1][k], a1);
        }
        out2[(size_t)(tblk * TB + i) * (EMBED / 2) + obase] = make_float2(a0, a1);
    }
}

// ---------------- fallback (fused, known-good R1) if ws too small ----------------
__global__ __launch_bounds__(512)
void fused_kernel(const int* __restrict__ tok,
                  const float* __restrict__ crt,
                  const float* __restrict__ cit,
                  const float* __restrict__ W,
                  const float* __restrict__ scale_p,
                  float* __restrict__ out)
{
    const int tid = threadIdx.x;
    const float s = scale_p[0];
    float w[4][NF];
    {
        const float4* W4 = reinterpret_cast<const float4*>(W + (size_t)tid * 4 * NF);
        #pragma unroll
        for (int r = 0; r < 4; ++r)
            #pragma unroll
            for (int k = 0; k < 4; ++k) {
                float4 v = W4[r * 4 + k];
                w[r][k * 4 + 0] = v.x; w[r][k * 4 + 1] = v.y;
                w[r][k * 4 + 2] = v.z; w[r][k * 4 + 3] = v.w;
            }
    }
    __shared__ float feats[64][NF];
    const int tok0 = blockIdx.x * 64;
    if (tid < 64) {
        const int t = tok[tok0 + tid];
        const float cr = crt[t], ci = cit[t];
        float zr = 0.0f, zi = 0.0f;
        #pragma unroll
        for (int st = 0; st < STEPS; ++st) {
            const float nzr = zr * zr - zi * zi + cr;
            const float nzi = 2.0f * zr * zi + ci;
            zr = nzr; zi = nzi;
            feats[tid][2 * st] = zr; feats[tid][2 * st + 1] = zi;
        }
    }
    __syncthreads();
    float4* out4 = reinterpret_cast<float4*>(out);
    for (int i = 0; i < 64; ++i) {
        float f[NF];
        const float4* fp = reinterpret_cast<const float4*>(feats[i]);
        #pragma unroll
        for (int k = 0; k < 4; ++k) {
            float4 v = fp[k];
            f[k * 4 + 0] = v.x; f[k * 4 + 1] = v.y;
            f[k * 4 + 2] = v.z; f[k * 4 + 3] = v.w;
        }
        float acc[4];
        #pragma unroll
        for (int r = 0; r < 4; ++r) {
            float a = 0.0f;
            #pragma unroll
            for (int k = 0; k < NF; ++k) a = fmaf(f[k], w[r][k], a);
            acc[r] = a * s;
        }
        out4[(size_t)(tok0 + i) * (EMBED / 4) + tid] =
            make_float4(acc[0], acc[1], acc[2], acc[3]);
    }
}

extern "C" void kernel_launch(void* const* d_in, const int* in_sizes, int n_in,
                              void* d_out, int out_size, void* d_ws, size_t ws_size,
                              hipStream_t stream) {
    const int*   tok   = (const int*)d_in[0];
    const float* crt   = (const float*)d_in[1];
    const float* cit   = (const float*)d_in[2];
    const float* W     = (const float*)d_in[3];
    const float* scale = (const float*)d_in[4];
    float*       out   = (float*)d_out;

    const size_t feats_bytes = (size_t)TOKENS * NF * sizeof(float);
    if (ws_size >= feats_bytes) {
        float* feats = (float*)d_ws;
        feats_kernel<<<TOKENS / 256, 256, 0, stream>>>(tok, crt, cit, feats);
        proj_kernel<<<4 * (TOKENS / TB), 256, 0, stream>>>(feats, W, scale, out);
    } else {
        fused_kernel<<<TOKENS / 64, 512, 0, stream>>>(tok, crt, cit, W, scale, out);
    }
}